// Round 23
// baseline (198.062 us; speedup 1.0000x reference)
//
#include <hip/hip_runtime.h>
#include <math.h>

#define DIM     1024
#define NHEAD   16
#define HD      64
#define BATCH   4
#define SEQ     2048
#define MTOT    (BATCH * SEQ)      // 8192
#define QKV_N   (3 * DIM)          // 3072

typedef __attribute__((ext_vector_type(8))) short bf16x8;
typedef __attribute__((ext_vector_type(4))) float f32x4;
typedef unsigned int u32;
typedef unsigned short u16;

__device__ __forceinline__ u16 f2bf(float f) {   // RNE fp32 -> bf16
    u32 u = __float_as_uint(f);
    return (u16)((u + 0x7fffu + ((u >> 16) & 1u)) >> 16);
}

__device__ __forceinline__ float exp2_fast(float x) {   // v_exp_f32 = 2^x
    float r; asm("v_exp_f32 %0, %1" : "=v"(r) : "v"(x)); return r;
}

__device__ __forceinline__ u32 cvtpk_bf16(float lo, float hi) {
    u32 r; asm("v_cvt_pk_bf16_f32 %0, %1, %2" : "=v"(r) : "v"(lo), "v"(hi));
    return r;
}

__device__ __forceinline__ u32 cvtpk_f16(float lo, float hi) {   // 2xfp16 pack
    u32 r; asm("v_cvt_pkrtz_f16_f32 %0, %1, %2" : "=v"(r) : "v"(lo), "v"(hi));
    return r;
}

__device__ __forceinline__ void gload_lds16(const u16* g, u16* l) {
    // async global->LDS, 16B/lane; dest = wave-uniform base + lane*16
    __builtin_amdgcn_global_load_lds((const __attribute__((address_space(1))) u32*)g,
                                     (__attribute__((address_space(3))) u32*)l, 16, 0, 0);
}

// ---------------------------------------------------------------------------
// Fused prep (single launch): blocks [0,8192) cast x fp32->bf16;
// [8192,8960) transpose+cast w_qkv; [8960,9216) transpose+cast w_proj.
// ---------------------------------------------------------------------------
__global__ __launch_bounds__(256) void prep(
    const float* __restrict__ x,  u16* __restrict__ xb,
    const float* __restrict__ wq, u16* __restrict__ wqt,
    const float* __restrict__ wp, u16* __restrict__ wpt)
{
    const int b = blockIdx.x;
    if (b < 8192) {   // cast x: 1024 f32 per block
        const int i = (b * 256 + threadIdx.x) * 4;
        const float4 v = *(const float4*)&x[i];
        ushort4 o;
        o.x = f2bf(v.x); o.y = f2bf(v.y); o.z = f2bf(v.z); o.w = f2bf(v.w);
        *(ushort4*)&xb[i] = o;
        return;
    }
    __shared__ float Ls[64][65];
    int i = b - 8192;
    const float* W; u16* Wt; int N;
    if (i < 768) { W = wq; Wt = wqt; N = QKV_N; }
    else         { i -= 768; W = wp; Wt = wpt; N = DIM; }
    const int k0 = (i & 15) * 64, n0 = (i >> 4) * 64;
    const int t = threadIdx.x;
    const int r = t >> 4, c4 = (t & 15) << 2;
    #pragma unroll
    for (int j = 0; j < 4; ++j) {
        const float4 v = *(const float4*)&W[(size_t)(k0 + r + j * 16) * N + n0 + c4];
        Ls[r + j * 16][c4 + 0] = v.x; Ls[r + j * 16][c4 + 1] = v.y;
        Ls[r + j * 16][c4 + 2] = v.z; Ls[r + j * 16][c4 + 3] = v.w;
    }
    __syncthreads();
    #pragma unroll
    for (int j = 0; j < 4; ++j) {
        const int nr = r + j * 16;
        ushort4 o;
        o.x = f2bf(Ls[c4 + 0][nr]); o.y = f2bf(Ls[c4 + 1][nr]);
        o.z = f2bf(Ls[c4 + 2][nr]); o.w = f2bf(Ls[c4 + 3][nr]);
        *(ushort4*)&Wt[(size_t)(n0 + nr) * DIM + k0 + c4] = o;
    }
}

// ===========================================================================
// bf16 MFMA GEMM, C[M][N] = A[M][K] * Bt[N][K]^T.  K = 1024.
// 128x128 tile, 4 waves (64x64 each, 4x4 frags), BK=32, global_load_lds w=16,
// source-swizzled LDS (slot ^= (row>>1)&3). 2-phase dbuf, 1 barrier/K-step.
// ===========================================================================
#define GEMM_STAGE(buf, kof, Aptr, Bptr)                                       \
    _Pragma("unroll") for (int i = 0; i < 2; ++i) {                            \
        const int row = w * 32 + i * 16 + (lane >> 2);                         \
        const int slot = (lane & 3) ^ ((row >> 1) & 3);                        \
        gload_lds16(&Aptr[(size_t)(m0 + row) * DIM + (kof) + slot * 8],        \
                    &As[buf][(w * 32 + i * 16) * 32]);                         \
        gload_lds16(&Bptr[(size_t)(n0 + row) * DIM + (kof) + slot * 8],        \
                    &Bs[buf][(w * 32 + i * 16) * 32]);                         \
    }

#define GEMM_MAINLOOP(Aptr, Bptr)                                              \
    __shared__ __align__(16) u16 As[2][128 * 32];                              \
    __shared__ __align__(16) u16 Bs[2][128 * 32];                              \
    const int t = threadIdx.x;                                                 \
    const int lane = t & 63, w = t >> 6;                                       \
    const int n0 = blockIdx.x * 128;                                           \
    const int m0 = blockIdx.y * 128;                                           \
    const int wm = (w & 1) * 64, wn = (w >> 1) * 64;                           \
    const int g = lane >> 4, li = lane & 15;                                   \
    f32x4 acc[4][4];                                                           \
    _Pragma("unroll") for (int mt = 0; mt < 4; ++mt)                           \
        _Pragma("unroll") for (int nt = 0; nt < 4; ++nt)                       \
            acc[mt][nt] = (f32x4){0.f, 0.f, 0.f, 0.f};                         \
    GEMM_STAGE(0, 0, Aptr, Bptr)                                               \
    __syncthreads();                                                           \
    int cur = 0;                                                               \
    for (int k0 = 0; k0 < DIM; k0 += 32) {                                     \
        if (k0 + 32 < DIM) { GEMM_STAGE(cur ^ 1, k0 + 32, Aptr, Bptr) }        \
        bf16x8 a[4], b[4];                                                     \
        _Pragma("unroll") for (int mt = 0; mt < 4; ++mt) {                     \
            const int row = wm + mt * 16 + li;                                 \
            const int slot = g ^ ((row >> 1) & 3);                             \
            a[mt] = *(const bf16x8*)&As[cur][row * 32 + slot * 8];             \
        }                                                                      \
        _Pragma("unroll") for (int nt = 0; nt < 4; ++nt) {                     \
            const int row = wn + nt * 16 + li;                                 \
            const int slot = g ^ ((row >> 1) & 3);                             \
            b[nt] = *(const bf16x8*)&Bs[cur][row * 32 + slot * 8];             \
        }                                                                      \
        _Pragma("unroll") for (int mt = 0; mt < 4; ++mt)                       \
            _Pragma("unroll") for (int nt = 0; nt < 4; ++nt)                   \
                acc[mt][nt] = __builtin_amdgcn_mfma_f32_16x16x32_bf16(         \
                    a[mt], b[nt], acc[mt][nt], 0, 0, 0);                       \
        __syncthreads();                                                       \
        cur ^= 1;                                                              \
    }

// QKV GEMM: scatter to q/k bf16 [B,H,N,hd]; V stored TRANSPOSED [B,H,hd,SEQ].
// Q pre-scaled by 0.125*log2(e) so attention softmax runs in exp2 domain.
#define QSCALE 0.18033688011112042f
__global__ __launch_bounds__(256) void gemm_qkv(
    const u16* __restrict__ A, const u16* __restrict__ Bt,
    const float* __restrict__ bias,
    u16* __restrict__ qo, u16* __restrict__ ko, u16* __restrict__ vo)
{
    GEMM_MAINLOOP(A, Bt)
    #pragma unroll
    for (int nt = 0; nt < 4; ++nt) {
        const int n = n0 + wn + nt * 16 + li;
        const int which = n >> 10;               // 0=q 1=k 2=v (uniform per nt)
        const int head  = (n >> 6) & 15;
        const int hd    = n & 63;
        const float bv = bias[n];
        if (which == 2) {
            #pragma unroll
            for (int mt = 0; mt < 4; ++mt) {
                const int m = m0 + wm + mt * 16 + g * 4;   // 4 consecutive toks
                const int bb = m >> 11, tok = m & 2047;
                const u32 p0 = cvtpk_bf16(acc[mt][nt][0] + bv, acc[mt][nt][1] + bv);
                const u32 p1 = cvtpk_bf16(acc[mt][nt][2] + bv, acc[mt][nt][3] + bv);
                u16* d = &vo[((size_t)(bb * NHEAD + head) * HD + hd) * SEQ + tok];
                *(u32*)&d[0] = p0;
                *(u32*)&d[2] = p1;
            }
        } else {
            u16* dst = (which == 0) ? qo : ko;
            const float scale = (which == 0) ? QSCALE : 1.0f;
            #pragma unroll
            for (int mt = 0; mt < 4; ++mt) {
                #pragma unroll
                for (int r = 0; r < 4; ++r) {
                    const int m = m0 + wm + mt * 16 + g * 4 + r;
                    const int bb = m >> 11, tok = m & 2047;
                    dst[((size_t)(bb * NHEAD + head) * SEQ + tok) * HD + hd] =
                        f2bf((acc[mt][nt][r] + bv) * scale);
                }
            }
        }
    }
}

// Projection GEMM (R20-proven 128x128): fp32 output + bias -> d_out.
__global__ __launch_bounds__(256) void gemm_proj(
    const u16* __restrict__ A, const u16* __restrict__ Bt,
    const float* __restrict__ bias, float* __restrict__ out)
{
    GEMM_MAINLOOP(A, Bt)
    #pragma unroll
    for (int nt = 0; nt < 4; ++nt) {
        const int n = n0 + wn + nt * 16 + li;
        const float bv = bias[n];
        #pragma unroll
        for (int mt = 0; mt < 4; ++mt) {
            #pragma unroll
            for (int r = 0; r < 4; ++r) {
                const int m = m0 + wm + mt * 16 + g * 4 + r;
                out[(size_t)m * DIM + n] = acc[mt][nt][r] + bv;
            }
        }
    }
}

// ===========================================================================
// MFMA flash attention R23: SPLIT-K over KV (2 halves x 16 tiles). Grid 1024
// = 4 blocks/CU = 32 waves/CU (2x R20 -- the kernel is latency-bound, all
// pipes <=41% at 2 blocks/CU). Fixed-m softmax makes the split ADDITIVE:
// partial O (fp16) and partial l (fp32) per half; merge = (O0+O1)/(l0+l1)
// in a tiny elementwise kernel. Wave shape / staging / kperm zero-LDS-P /
// XCD chunking identical to R20 (conflicts 0). LDS 32 KB.
// ===========================================================================
#define NKT  (SEQ / 64)
#define ATTN_STAGE(buf, ktile)                                                 \
    {                                                                          \
        gload_lds16(&kg[(size_t)(ktile) * (64 * HD) + (size_t)key * HD + sl],  \
                    &Ks[buf][(w * 8) * 64]);                                   \
        gload_lds16(&vg[(size_t)rho * SEQ + (ktile) * 64 + sl],                \
                    &Vs[buf][(w * 8) * 64]);                                   \
    }

__global__ __launch_bounds__(512) void attn_mfma(
    const u16* __restrict__ q, const u16* __restrict__ k,
    const u16* __restrict__ v, u16* __restrict__ po, float* __restrict__ pl)
{
    __shared__ __align__(16) u16 Ks[2][64 * 64];
    __shared__ __align__(16) u16 Vs[2][64 * 64];

    const int t = threadIdx.x;
    const int lane = t & 63, w = t >> 6;        // w = 0..7
    const int g = lane >> 4, li = lane & 15;

    // XCD-chunked swizzle: 1024 blocks = 8 XCDs x 128; 8 consecutive bh/XCD
    int flat = blockIdx.y * 16 + blockIdx.x;    // gridDim.x = 16
    flat = (flat & 7) * 128 + (flat >> 3);
    const int bh   = flat >> 4;
    const int half = (flat >> 3) & 1;
    const int q0   = (flat & 7) * 256;
    const size_t base = (size_t)bh * SEQ * HD;
    const u16* kg = k + base;
    const u16* vg = v + (size_t)bh * HD * SEQ;   // V^T [hd][SEQ]

    // Q B-frags, both halves: q-col = li, d-slice = ks*32 + g*8
    bf16x8 qf[2][2];
    #pragma unroll
    for (int h = 0; h < 2; ++h) {
        const size_t qrow = base + (size_t)(q0 + w * 32 + h * 16 + li) * HD;
        qf[h][0] = *(const bf16x8*)&q[qrow + g * 8];
        qf[h][1] = *(const bf16x8*)&q[qrow + 32 + g * 8];
    }

    float lsum[2] = {0.f, 0.f};
    f32x4 oacc[2][4];
    #pragma unroll
    for (int h = 0; h < 2; ++h)
        #pragma unroll
        for (int nt = 0; nt < 4; ++nt) oacc[h][nt] = (f32x4){0.f, 0.f, 0.f, 0.f};

    // staging map: wave w stages LDS rows [w*8, w*8+8) of K (kperm'd) and V^T
    const int srow = lane >> 3;                // 0..7 within wave's chunk
    const int sslot = lane & 7;                // 16B slot within row
    const int rho = w * 8 + srow;              // LDS row (K: mfma row; V: hd)
    const int key = (rho & 32) | (((rho >> 2) & 3) << 3)
                  | (((rho >> 4) & 1) << 2) | (rho & 3);   // global key for rho
    const int sl = (sslot ^ (rho & 7)) << 3;   // pre-swizzled source chunk
    const int x8 = li & 7;

    const int kt0 = half * (NKT / 2);          // this block's 16 KV tiles
    ATTN_STAGE(0, kt0)
    __syncthreads();

    int cur = 0;
    for (int kt = kt0; kt < kt0 + NKT / 2; ++kt) {
        if (kt + 1 < kt0 + NKT / 2) { ATTN_STAGE(cur ^ 1, kt + 1) }
        const u16* Kc = Ks[cur];
        const u16* Vc = Vs[cur];

        // QK^T: s[h][nt][r] = S[key=kperm(16nt+4g+r)][q=li]
        f32x4 s[2][4];
        __builtin_amdgcn_s_setprio(1);
        #pragma unroll
        for (int nt = 0; nt < 4; ++nt) {
            const int rowb = (nt * 16 + li) << 6;
            const bf16x8 kf0 = *(const bf16x8*)&Kc[rowb + ((g ^ x8) << 3)];
            const bf16x8 kf1 = *(const bf16x8*)&Kc[rowb + (((g ^ 4) ^ x8) << 3)];
            #pragma unroll
            for (int h = 0; h < 2; ++h) {
                f32x4 c = (f32x4){0.f, 0.f, 0.f, 0.f};
                c = __builtin_amdgcn_mfma_f32_16x16x32_bf16(kf0, qf[h][0], c, 0, 0, 0);
                c = __builtin_amdgcn_mfma_f32_16x16x32_bf16(kf1, qf[h][1], c, 0, 0, 0);
                s[h][nt] = c;
            }
        }
        __builtin_amdgcn_s_setprio(0);

        // fixed-m softmax + in-register P pack (kperm makes pb = own regs)
        bf16x8 pb[2][2];
        #pragma unroll
        for (int h = 0; h < 2; ++h) {
            float rs = 0.f;
            #pragma unroll
            for (int nt = 0; nt < 4; ++nt)
                #pragma unroll
                for (int r = 0; r < 4; ++r) {
                    const float p = exp2_fast(s[h][nt][r]);
                    s[h][nt][r] = p;
                    rs += p;
                }
            lsum[h] += rs;
            #pragma unroll
            for (int ks = 0; ks < 2; ++ks) {
                union { u32 u[4]; bf16x8 v8; } uu;
                uu.u[0] = cvtpk_bf16(s[h][2 * ks][0],     s[h][2 * ks][1]);
                uu.u[1] = cvtpk_bf16(s[h][2 * ks][2],     s[h][2 * ks][3]);
                uu.u[2] = cvtpk_bf16(s[h][2 * ks + 1][0], s[h][2 * ks + 1][1]);
                uu.u[3] = cvtpk_bf16(s[h][2 * ks + 1][2], s[h][2 * ks + 1][3]);
                pb[h][ks] = uu.v8;
            }
        }

        // PV: O^T[hd][q] += V^T[hd][key] * P^T[key][q]
        __builtin_amdgcn_s_setprio(1);
        #pragma unroll
        for (int ks = 0; ks < 2; ++ks) {
            #pragma unroll
            for (int nt = 0; nt < 4; ++nt) {
                const bf16x8 vb = *(const bf16x8*)
                    &Vc[((nt * 16 + li) << 6) + (((g ^ (ks << 2)) ^ x8) << 3)];
                #pragma unroll
                for (int h = 0; h < 2; ++h)
                    oacc[h][nt] = __builtin_amdgcn_mfma_f32_16x16x32_bf16(
                        vb, pb[h][ks], oacc[h][nt], 0, 0, 0);
            }
        }
        __builtin_amdgcn_s_setprio(0);

        __syncthreads();   // drains gload_lds (vmcnt 0) + protects buffers
        cur ^= 1;
    }

    // epilogue: reduce l over g-groups; store fp16 partial O + fp32 partial l
    u16*  poW = po + ((size_t)(half * 64 + bh) * 2048) * 64;
    float* plW = pl + (size_t)(half * 64 + bh) * 2048;
    #pragma unroll
    for (int h = 0; h < 2; ++h) {
        float lf = lsum[h];
        lf += __shfl_xor(lf, 16);
        lf += __shfl_xor(lf, 32);
        const int tok = q0 + w * 32 + h * 16 + li;
        if (g == 0) plW[tok] = lf;
        #pragma unroll
        for (int nt = 0; nt < 4; ++nt) {
            const u32 p0 = cvtpk_f16(oacc[h][nt][0], oacc[h][nt][1]);
            const u32 p1 = cvtpk_f16(oacc[h][nt][2], oacc[h][nt][3]);
            *(u32*)&poW[(size_t)tok * 64 + nt * 16 + g * 4]     = p0;
            *(u32*)&poW[(size_t)tok * 64 + nt * 16 + g * 4 + 2] = p1;
        }
    }
}

// Merge: ao[bh,tok,hd] = (po[0]+po[1]) / (pl[0]+pl[1]), bf16 out [B,N,D].
__global__ __launch_bounds__(256) void attn_merge(
    const u16* __restrict__ po, const float* __restrict__ pl,
    u16* __restrict__ ao)
{
    const size_t e = ((size_t)blockIdx.x * 256 + threadIdx.x) * 8;
    const int hd8 = (int)(e & 63);
    const int tok = (int)((e >> 6) & 2047);
    const int bh  = (int)(e >> 17);
    union { uint4 u; _Float16 h[8]; } a, b;
    a.u = *(const uint4*)&po[((size_t)bh * 2048 + tok) * 64 + hd8];
    b.u = *(const uint4*)&po[((size_t)(64 + bh) * 2048 + tok) * 64 + hd8];
    const float inv = 1.0f / (pl[bh * 2048 + tok] + pl[(64 + bh) * 2048 + tok]);
    const int bb = bh >> 4, hh = bh & 15;
    u32 o[4];
    #pragma unroll
    for (int i = 0; i < 4; ++i)
        o[i] = cvtpk_bf16(((float)a.h[2 * i]     + (float)b.h[2 * i])     * inv,
                          ((float)a.h[2 * i + 1] + (float)b.h[2 * i + 1]) * inv);
    *(uint4*)&ao[((size_t)(bb * SEQ + tok)) * DIM + hh * HD + hd8] = *(uint4*)o;
}

extern "C" void kernel_launch(void* const* d_in, const int* in_sizes, int n_in,
                              void* d_out, int out_size, void* d_ws, size_t ws_size,
                              hipStream_t stream)
{
    const float* x      = (const float*)d_in[0];
    const float* w_qkv  = (const float*)d_in[1];
    const float* b_qkv  = (const float*)d_in[2];
    const float* w_proj = (const float*)d_in[3];
    const float* b_proj = (const float*)d_in[4];
    float* out = (float*)d_out;

    // workspace (121 MB total; harness ws proven >= 128 MB in R0)
    u16* xb  = (u16*)d_ws;                         // 8192x1024 bf16
    u16* wqt = xb  + (size_t)MTOT * DIM;           // 3072x1024 (transposed)
    u16* wpt = wqt + (size_t)QKV_N * DIM;          // 1024x1024 (transposed)
    u16* qb  = wpt + (size_t)DIM * DIM;            // [B,H,N,hd]
    u16* kb  = qb  + (size_t)MTOT * DIM;
    u16* vb  = kb  + (size_t)MTOT * DIM;           // V^T [B,H,hd,SEQ]
    u16* aob = vb  + (size_t)MTOT * DIM;           // [B,N,D]
    u16* po  = aob + (size_t)MTOT * DIM;           // fp16 [2][64][2048][64]
    float* pl = (float*)(po + (size_t)2 * 64 * 2048 * 64);  // fp32 [2][64][2048]

    prep<<<8192 + 768 + 256, 256, 0, stream>>>(x, xb, w_qkv, wqt, w_proj, wpt);
    gemm_qkv<<<dim3(QKV_N / 128, MTOT / 128), 256, 0, stream>>>(xb, wqt, b_qkv, qb, kb, vb);
    attn_mfma<<<dim3(16, BATCH * NHEAD), 512, 0, stream>>>(qb, kb, vb, po, pl);
    attn_merge<<<(64 * 2048 * 64) / (256 * 8), 256, 0, stream>>>(po, pl, aob);
    gemm_proj<<<dim3(DIM / 128, MTOT / 128), 256, 0, stream>>>(aob, wpt, b_proj, out);
}

// Round 24
// 190.028 us; speedup vs baseline: 1.0423x; 1.0423x over previous
//
#include <hip/hip_runtime.h>
#include <math.h>

#define DIM     1024
#define NHEAD   16
#define HD      64
#define BATCH   4
#define SEQ     2048
#define MTOT    (BATCH * SEQ)      // 8192
#define QKV_N   (3 * DIM)          // 3072

typedef __attribute__((ext_vector_type(8))) short bf16x8;
typedef __attribute__((ext_vector_type(4))) float f32x4;
typedef unsigned int u32;
typedef unsigned short u16;

__device__ __forceinline__ u16 f2bf(float f) {   // RNE fp32 -> bf16
    u32 u = __float_as_uint(f);
    return (u16)((u + 0x7fffu + ((u >> 16) & 1u)) >> 16);
}

__device__ __forceinline__ float exp2_fast(float x) {   // v_exp_f32 = 2^x
    float r; asm("v_exp_f32 %0, %1" : "=v"(r) : "v"(x)); return r;
}

__device__ __forceinline__ u32 cvtpk_bf16(float lo, float hi) {
    u32 r; asm("v_cvt_pk_bf16_f32 %0, %1, %2" : "=v"(r) : "v"(lo), "v"(hi));
    return r;
}

__device__ __forceinline__ void gload_lds16(const u16* g, u16* l) {
    // async global->LDS, 16B/lane; dest = wave-uniform base + lane*16
    __builtin_amdgcn_global_load_lds((const __attribute__((address_space(1))) u32*)g,
                                     (__attribute__((address_space(3))) u32*)l, 16, 0, 0);
}

// ---------------------------------------------------------------------------
// Fused prep (single launch): blocks [0,8192) cast x fp32->bf16;
// [8192,8960) transpose+cast w_qkv; [8960,9216) transpose+cast w_proj.
// ---------------------------------------------------------------------------
__global__ __launch_bounds__(256) void prep(
    const float* __restrict__ x,  u16* __restrict__ xb,
    const float* __restrict__ wq, u16* __restrict__ wqt,
    const float* __restrict__ wp, u16* __restrict__ wpt)
{
    const int b = blockIdx.x;
    if (b < 8192) {   // cast x: 1024 f32 per block
        const int i = (b * 256 + threadIdx.x) * 4;
        const float4 v = *(const float4*)&x[i];
        ushort4 o;
        o.x = f2bf(v.x); o.y = f2bf(v.y); o.z = f2bf(v.z); o.w = f2bf(v.w);
        *(ushort4*)&xb[i] = o;
        return;
    }
    __shared__ float Ls[64][65];
    int i = b - 8192;
    const float* W; u16* Wt; int N;
    if (i < 768) { W = wq; Wt = wqt; N = QKV_N; }
    else         { i -= 768; W = wp; Wt = wpt; N = DIM; }
    const int k0 = (i & 15) * 64, n0 = (i >> 4) * 64;
    const int t = threadIdx.x;
    const int r = t >> 4, c4 = (t & 15) << 2;
    #pragma unroll
    for (int j = 0; j < 4; ++j) {
        const float4 v = *(const float4*)&W[(size_t)(k0 + r + j * 16) * N + n0 + c4];
        Ls[r + j * 16][c4 + 0] = v.x; Ls[r + j * 16][c4 + 1] = v.y;
        Ls[r + j * 16][c4 + 2] = v.z; Ls[r + j * 16][c4 + 3] = v.w;
    }
    __syncthreads();
    #pragma unroll
    for (int j = 0; j < 4; ++j) {
        const int nr = r + j * 16;
        ushort4 o;
        o.x = f2bf(Ls[c4 + 0][nr]); o.y = f2bf(Ls[c4 + 1][nr]);
        o.z = f2bf(Ls[c4 + 2][nr]); o.w = f2bf(Ls[c4 + 3][nr]);
        *(ushort4*)&Wt[(size_t)(n0 + nr) * DIM + k0 + c4] = o;
    }
}

// ===========================================================================
// bf16 MFMA GEMM, C[M][N] = A[M][K] * Bt[N][K]^T.  K = 1024.
// 128x128 tile, 4 waves (64x64 each, 4x4 frags), BK=32, global_load_lds w=16,
// source-swizzled LDS (slot ^= (row>>1)&3). 2-phase dbuf, 1 barrier/K-step.
// ===========================================================================
#define GEMM_STAGE(buf, kof, Aptr, Bptr)                                       \
    _Pragma("unroll") for (int i = 0; i < 2; ++i) {                            \
        const int row = w * 32 + i * 16 + (lane >> 2);                         \
        const int slot = (lane & 3) ^ ((row >> 1) & 3);                        \
        gload_lds16(&Aptr[(size_t)(m0 + row) * DIM + (kof) + slot * 8],        \
                    &As[buf][(w * 32 + i * 16) * 32]);                         \
        gload_lds16(&Bptr[(size_t)(n0 + row) * DIM + (kof) + slot * 8],        \
                    &Bs[buf][(w * 32 + i * 16) * 32]);                         \
    }

#define GEMM_MAINLOOP(Aptr, Bptr)                                              \
    __shared__ __align__(16) u16 As[2][128 * 32];                              \
    __shared__ __align__(16) u16 Bs[2][128 * 32];                              \
    const int t = threadIdx.x;                                                 \
    const int lane = t & 63, w = t >> 6;                                       \
    const int n0 = blockIdx.x * 128;                                           \
    const int m0 = blockIdx.y * 128;                                           \
    const int wm = (w & 1) * 64, wn = (w >> 1) * 64;                           \
    const int g = lane >> 4, li = lane & 15;                                   \
    f32x4 acc[4][4];                                                           \
    _Pragma("unroll") for (int mt = 0; mt < 4; ++mt)                           \
        _Pragma("unroll") for (int nt = 0; nt < 4; ++nt)                       \
            acc[mt][nt] = (f32x4){0.f, 0.f, 0.f, 0.f};                         \
    GEMM_STAGE(0, 0, Aptr, Bptr)                                               \
    __syncthreads();                                                           \
    int cur = 0;                                                               \
    for (int k0 = 0; k0 < DIM; k0 += 32) {                                     \
        if (k0 + 32 < DIM) { GEMM_STAGE(cur ^ 1, k0 + 32, Aptr, Bptr) }        \
        bf16x8 a[4], b[4];                                                     \
        _Pragma("unroll") for (int mt = 0; mt < 4; ++mt) {                     \
            const int row = wm + mt * 16 + li;                                 \
            const int slot = g ^ ((row >> 1) & 3);                             \
            a[mt] = *(const bf16x8*)&As[cur][row * 32 + slot * 8];             \
        }                                                                      \
        _Pragma("unroll") for (int nt = 0; nt < 4; ++nt) {                     \
            const int row = wn + nt * 16 + li;                                 \
            const int slot = g ^ ((row >> 1) & 3);                             \
            b[nt] = *(const bf16x8*)&Bs[cur][row * 32 + slot * 8];             \
        }                                                                      \
        _Pragma("unroll") for (int mt = 0; mt < 4; ++mt)                       \
            _Pragma("unroll") for (int nt = 0; nt < 4; ++nt)                   \
                acc[mt][nt] = __builtin_amdgcn_mfma_f32_16x16x32_bf16(         \
                    a[mt], b[nt], acc[mt][nt], 0, 0, 0);                       \
        __syncthreads();                                                       \
        cur ^= 1;                                                              \
    }

// QKV GEMM: scatter to q/k bf16 [B,H,N,hd]; V stored TRANSPOSED [B,H,hd,SEQ].
// Q pre-scaled by 0.125*log2(e) so attention softmax runs in exp2 domain.
#define QSCALE 0.18033688011112042f
__global__ __launch_bounds__(256) void gemm_qkv(
    const u16* __restrict__ A, const u16* __restrict__ Bt,
    const float* __restrict__ bias,
    u16* __restrict__ qo, u16* __restrict__ ko, u16* __restrict__ vo)
{
    GEMM_MAINLOOP(A, Bt)
    #pragma unroll
    for (int nt = 0; nt < 4; ++nt) {
        const int n = n0 + wn + nt * 16 + li;
        const int which = n >> 10;               // 0=q 1=k 2=v (uniform per nt)
        const int head  = (n >> 6) & 15;
        const int hd    = n & 63;
        const float bv = bias[n];
        if (which == 2) {
            #pragma unroll
            for (int mt = 0; mt < 4; ++mt) {
                const int m = m0 + wm + mt * 16 + g * 4;   // 4 consecutive toks
                const int bb = m >> 11, tok = m & 2047;
                const u32 p0 = cvtpk_bf16(acc[mt][nt][0] + bv, acc[mt][nt][1] + bv);
                const u32 p1 = cvtpk_bf16(acc[mt][nt][2] + bv, acc[mt][nt][3] + bv);
                u16* d = &vo[((size_t)(bb * NHEAD + head) * HD + hd) * SEQ + tok];
                *(u32*)&d[0] = p0;
                *(u32*)&d[2] = p1;
            }
        } else {
            u16* dst = (which == 0) ? qo : ko;
            const float scale = (which == 0) ? QSCALE : 1.0f;
            #pragma unroll
            for (int mt = 0; mt < 4; ++mt) {
                #pragma unroll
                for (int r = 0; r < 4; ++r) {
                    const int m = m0 + wm + mt * 16 + g * 4 + r;
                    const int bb = m >> 11, tok = m & 2047;
                    dst[((size_t)(bb * NHEAD + head) * SEQ + tok) * HD + hd] =
                        f2bf((acc[mt][nt][r] + bv) * scale);
                }
            }
        }
    }
}

// Projection GEMM (128x128): fp32 output + bias -> d_out.
__global__ __launch_bounds__(256) void gemm_proj(
    const u16* __restrict__ A, const u16* __restrict__ Bt,
    const float* __restrict__ bias, float* __restrict__ out)
{
    GEMM_MAINLOOP(A, Bt)
    #pragma unroll
    for (int nt = 0; nt < 4; ++nt) {
        const int n = n0 + wn + nt * 16 + li;
        const float bv = bias[n];
        #pragma unroll
        for (int mt = 0; mt < 4; ++mt) {
            #pragma unroll
            for (int r = 0; r < 4; ++r) {
                const int m = m0 + wm + mt * 16 + g * 4 + r;
                out[(size_t)m * DIM + n] = acc[mt][nt][r] + bv;
            }
        }
    }
}

// ===========================================================================
// MFMA flash attention (R20-proven): 8 waves, QBLK=256, all staging via
// global_load_lds (conflicts 0), V^T layout, kperm zero-LDS-P, fixed-m
// softmax, 2-slot dbuf + one __syncthreads per tile, setprio on MFMA
// clusters, XCD-chunked block swizzle (FETCH 24.6 MB measured).
// ===========================================================================
#define NKT  (SEQ / 64)
#define ATTN_STAGE(buf, ktile)                                                 \
    {                                                                          \
        gload_lds16(&kg[(size_t)(ktile) * (64 * HD) + (size_t)key * HD + sl],  \
                    &Ks[buf][(w * 8) * 64]);                                   \
        gload_lds16(&vg[(size_t)rho * SEQ + (ktile) * 64 + sl],                \
                    &Vs[buf][(w * 8) * 64]);                                   \
    }

__global__ __launch_bounds__(512) void attn_mfma(
    const u16* __restrict__ q, const u16* __restrict__ k,
    const u16* __restrict__ v, u16* __restrict__ ao)
{
    __shared__ __align__(16) u16 Ks[2][64 * 64];
    __shared__ __align__(16) u16 Vs[2][64 * 64];

    const int t = threadIdx.x;
    const int lane = t & 63, w = t >> 6;        // w = 0..7
    const int g = lane >> 4, li = lane & 15;

    // XCD-chunked swizzle (512 blocks): xcd = flat&7 owns 64 consecutive swz
    int flat = blockIdx.y * 8 + blockIdx.x;     // gridDim.x = 8
    flat = (flat & 7) * 64 + (flat >> 3);
    const int q0 = (flat & 7) * 256;
    const int bh = flat >> 3;
    const size_t base = (size_t)bh * SEQ * HD;
    const u16* kg = k + base;
    const u16* vg = v + (size_t)bh * HD * SEQ;   // V^T [hd][SEQ]

    // Q B-frags, both halves: q-col = li, d-slice = ks*32 + g*8
    bf16x8 qf[2][2];
    #pragma unroll
    for (int h = 0; h < 2; ++h) {
        const size_t qrow = base + (size_t)(q0 + w * 32 + h * 16 + li) * HD;
        qf[h][0] = *(const bf16x8*)&q[qrow + g * 8];
        qf[h][1] = *(const bf16x8*)&q[qrow + 32 + g * 8];
    }

    float lsum[2] = {0.f, 0.f};
    f32x4 oacc[2][4];
    #pragma unroll
    for (int h = 0; h < 2; ++h)
        #pragma unroll
        for (int nt = 0; nt < 4; ++nt) oacc[h][nt] = (f32x4){0.f, 0.f, 0.f, 0.f};

    // staging map: wave w stages LDS rows [w*8, w*8+8) of K (kperm'd) and V^T
    const int srow = lane >> 3;                // 0..7 within wave's chunk
    const int sslot = lane & 7;                // 16B slot within row
    const int rho = w * 8 + srow;              // LDS row (K: mfma row; V: hd)
    const int key = (rho & 32) | (((rho >> 2) & 3) << 3)
                  | (((rho >> 4) & 1) << 2) | (rho & 3);   // global key for rho
    const int sl = (sslot ^ (rho & 7)) << 3;   // pre-swizzled source chunk
    const int x8 = li & 7;

    ATTN_STAGE(0, 0)
    __syncthreads();

    int cur = 0;
    for (int kt = 0; kt < NKT; ++kt) {
        if (kt + 1 < NKT) { ATTN_STAGE(cur ^ 1, kt + 1) }
        const u16* Kc = Ks[cur];
        const u16* Vc = Vs[cur];

        // QK^T: s[h][nt][r] = S[key=kperm(16nt+4g+r)][q=li]
        f32x4 s[2][4];
        __builtin_amdgcn_s_setprio(1);
        #pragma unroll
        for (int nt = 0; nt < 4; ++nt) {
            const int rowb = (nt * 16 + li) << 6;
            const bf16x8 kf0 = *(const bf16x8*)&Kc[rowb + ((g ^ x8) << 3)];
            const bf16x8 kf1 = *(const bf16x8*)&Kc[rowb + (((g ^ 4) ^ x8) << 3)];
            #pragma unroll
            for (int h = 0; h < 2; ++h) {
                f32x4 c = (f32x4){0.f, 0.f, 0.f, 0.f};
                c = __builtin_amdgcn_mfma_f32_16x16x32_bf16(kf0, qf[h][0], c, 0, 0, 0);
                c = __builtin_amdgcn_mfma_f32_16x16x32_bf16(kf1, qf[h][1], c, 0, 0, 0);
                s[h][nt] = c;
            }
        }
        __builtin_amdgcn_s_setprio(0);

        // fixed-m softmax + in-register P pack (kperm makes pb = own regs)
        bf16x8 pb[2][2];
        #pragma unroll
        for (int h = 0; h < 2; ++h) {
            float rs = 0.f;
            #pragma unroll
            for (int nt = 0; nt < 4; ++nt)
                #pragma unroll
                for (int r = 0; r < 4; ++r) {
                    const float p = exp2_fast(s[h][nt][r]);
                    s[h][nt][r] = p;
                    rs += p;
                }
            lsum[h] += rs;
            #pragma unroll
            for (int ks = 0; ks < 2; ++ks) {
                union { u32 u[4]; bf16x8 v8; } uu;
                uu.u[0] = cvtpk_bf16(s[h][2 * ks][0],     s[h][2 * ks][1]);
                uu.u[1] = cvtpk_bf16(s[h][2 * ks][2],     s[h][2 * ks][3]);
                uu.u[2] = cvtpk_bf16(s[h][2 * ks + 1][0], s[h][2 * ks + 1][1]);
                uu.u[3] = cvtpk_bf16(s[h][2 * ks + 1][2], s[h][2 * ks + 1][3]);
                pb[h][ks] = uu.v8;
            }
        }

        // PV: O^T[hd][q] += V^T[hd][key] * P^T[key][q]
        __builtin_amdgcn_s_setprio(1);
        #pragma unroll
        for (int ks = 0; ks < 2; ++ks) {
            #pragma unroll
            for (int nt = 0; nt < 4; ++nt) {
                const bf16x8 vb = *(const bf16x8*)
                    &Vc[((nt * 16 + li) << 6) + (((g ^ (ks << 2)) ^ x8) << 3)];
                #pragma unroll
                for (int h = 0; h < 2; ++h)
                    oacc[h][nt] = __builtin_amdgcn_mfma_f32_16x16x32_bf16(
                        vb, pb[h][ks], oacc[h][nt], 0, 0, 0);
            }
        }
        __builtin_amdgcn_s_setprio(0);

        __syncthreads();   // drains gload_lds (vmcnt 0) + protects buffers
        cur ^= 1;
    }

    // epilogue: reduce l over g-groups (each lane owns q=li), normalize, store
    const int bb = bh >> 4, hh = bh & 15;
    #pragma unroll
    for (int h = 0; h < 2; ++h) {
        float lf = lsum[h];
        lf += __shfl_xor(lf, 16);
        lf += __shfl_xor(lf, 32);
        const float inv = 1.0f / lf;
        const int tok = q0 + w * 32 + h * 16 + li;
        u16* dst = &ao[(size_t)(bb * SEQ + tok) * DIM + hh * HD];
        #pragma unroll
        for (int nt = 0; nt < 4; ++nt) {
            const u32 p0 = cvtpk_bf16(oacc[h][nt][0] * inv, oacc[h][nt][1] * inv);
            const u32 p1 = cvtpk_bf16(oacc[h][nt][2] * inv, oacc[h][nt][3] * inv);
            *(u32*)&dst[nt * 16 + g * 4]     = p0;
            *(u32*)&dst[nt * 16 + g * 4 + 2] = p1;
        }
    }
}

extern "C" void kernel_launch(void* const* d_in, const int* in_sizes, int n_in,
                              void* d_out, int out_size, void* d_ws, size_t ws_size,
                              hipStream_t stream)
{
    const float* x      = (const float*)d_in[0];
    const float* w_qkv  = (const float*)d_in[1];
    const float* b_qkv  = (const float*)d_in[2];
    const float* w_proj = (const float*)d_in[3];
    const float* b_proj = (const float*)d_in[4];
    float* out = (float*)d_out;

    // bf16 workspace (~92 MB)
    u16* xb  = (u16*)d_ws;                         // 8192x1024
    u16* wqt = xb  + (size_t)MTOT * DIM;           // 3072x1024 (transposed)
    u16* wpt = wqt + (size_t)QKV_N * DIM;          // 1024x1024 (transposed)
    u16* qb  = wpt + (size_t)DIM * DIM;            // [B,H,N,hd]
    u16* kb  = qb  + (size_t)MTOT * DIM;
    u16* vb  = kb  + (size_t)MTOT * DIM;           // V^T [B,H,hd,SEQ]
    u16* aob = vb  + (size_t)MTOT * DIM;           // [B,N,D]

    prep<<<8192 + 768 + 256, 256, 0, stream>>>(x, xb, w_qkv, wqt, w_proj, wpt);
    gemm_qkv<<<dim3(QKV_N / 128, MTOT / 128), 256, 0, stream>>>(xb, wqt, b_qkv, qb, kb, vb);
    attn_mfma<<<dim3(SEQ / 256, BATCH * NHEAD), 512, 0, stream>>>(qb, kb, vb, aob);
    gemm_proj<<<dim3(DIM / 128, MTOT / 128), 256, 0, stream>>>(aob, wpt, b_proj, out);
}